// Round 3
// baseline (1379.235 us; speedup 1.0000x reference)
//
#include <hip/hip_runtime.h>

#define BB 16
#define CC 256
#define HW 4096
#define TD3 768
#define TD2 512

typedef __bf16 bf16x8 __attribute__((ext_vector_type(8)));
typedef float f32x4 __attribute__((ext_vector_type(4)));

__device__ inline ushort f2bf(float f) {
    union { float f; uint u; } v; v.f = f;
    uint u = v.u;
    return (ushort)((u + 0x7FFFu + ((u >> 16) & 1u)) >> 16);
}
__device__ inline float bf2f(ushort h) {
    union { uint u; float f; } v; v.u = ((uint)h) << 16;
    return v.f;
}
__device__ inline uint pack2(float a, float b) {
    return (uint)f2bf(a) | ((uint)f2bf(b) << 16);
}

// ---------------- K0: x (B,C,HW) f32 -> x_cl (B,HW,C) bf16 ----------------
__launch_bounds__(256)
__global__ void k0_transpose(const float* __restrict__ x, ushort* __restrict__ x_cl) {
    __shared__ float tile[64][65];
    int b = blockIdx.z;
    int n0 = blockIdx.x * 64;
    int c0 = blockIdx.y * 64;
    int t = threadIdx.x;
    const float* xp = x + ((size_t)b * CC + c0) * HW + n0;
    int nl = t & 63;
    int cl0 = t >> 6;
#pragma unroll
    for (int i = 0; i < 16; i++) {
        int cl = cl0 + i * 4;
        tile[cl][nl] = xp[(size_t)cl * HW + nl];
    }
    __syncthreads();
#pragma unroll
    for (int it = 0; it < 2; it++) {
        int item = t + it * 256;
        int n = item >> 3;
        int cc = item & 7;
        uint4 o;
        o.x = pack2(tile[cc * 8 + 0][n], tile[cc * 8 + 1][n]);
        o.y = pack2(tile[cc * 8 + 2][n], tile[cc * 8 + 3][n]);
        o.z = pack2(tile[cc * 8 + 4][n], tile[cc * 8 + 5][n]);
        o.w = pack2(tile[cc * 8 + 6][n], tile[cc * 8 + 7][n]);
        *(uint4*)(x_cl + ((size_t)b * HW + n0 + n) * CC + c0 + cc * 8) = o;
    }
}

// ---------------- K1: qkv_cl[b][n][o] = sum_c x_cl[b][n][c] * w_qkv[o][c], f32 out, split-B ----------------
__launch_bounds__(256)
__global__ void k1_qkv(const ushort* __restrict__ x_cl, const float* __restrict__ w_qkv,
                       float* __restrict__ qkv_cl) {
    __shared__ ushort Ald[128][40];
    __shared__ ushort Bh[128][40];
    __shared__ ushort Bl[128][40];
    int b = blockIdx.z;
    int n0 = blockIdx.x * 128;
    int o0 = blockIdx.y * 128;
    int t = threadIdx.x;
    int w = t >> 6, l = t & 63;
    int wn = (w >> 1) * 64, wo = (w & 1) * 64;
    f32x4 acc[4][4];
#pragma unroll
    for (int m = 0; m < 4; m++)
#pragma unroll
        for (int o = 0; o < 4; o++)
#pragma unroll
            for (int r = 0; r < 4; r++) acc[m][o][r] = 0.f;

    const ushort* Ap = x_cl + ((size_t)b * HW + n0) * CC;
    const float* Bp = w_qkv + (size_t)o0 * CC;

    for (int k0 = 0; k0 < CC; k0 += 32) {
#pragma unroll
        for (int it = 0; it < 2; it++) {
            int id = t + it * 256;
            int r = id >> 2, q = id & 3;
            uint4 v = *(const uint4*)(Ap + (size_t)r * CC + k0 + q * 8);
            *(uint4*)&Ald[r][q * 8] = v;
        }
#pragma unroll
        for (int it = 0; it < 2; it++) {
            int id = t + it * 256;
            int r = id >> 2, q = id & 3;
            const float* src = Bp + (size_t)r * CC + k0 + q * 8;
            float f[8];
            *(float4*)&f[0] = *(const float4*)src;
            *(float4*)&f[4] = *(const float4*)(src + 4);
            ushort hi[8]; float lo[8];
#pragma unroll
            for (int j = 0; j < 8; j++) { hi[j] = f2bf(f[j]); lo[j] = f[j] - bf2f(hi[j]); }
            uint4 hv, lv;
            hv.x = (uint)hi[0] | ((uint)hi[1] << 16); hv.y = (uint)hi[2] | ((uint)hi[3] << 16);
            hv.z = (uint)hi[4] | ((uint)hi[5] << 16); hv.w = (uint)hi[6] | ((uint)hi[7] << 16);
            lv.x = pack2(lo[0], lo[1]); lv.y = pack2(lo[2], lo[3]);
            lv.z = pack2(lo[4], lo[5]); lv.w = pack2(lo[6], lo[7]);
            *(uint4*)&Bh[r][q * 8] = hv;
            *(uint4*)&Bl[r][q * 8] = lv;
        }
        __syncthreads();
        bf16x8 af[4], bh[4], bl[4];
#pragma unroll
        for (int m = 0; m < 4; m++) af[m] = *(const bf16x8*)&Ald[wn + m * 16 + (l & 15)][(l >> 4) * 8];
#pragma unroll
        for (int o = 0; o < 4; o++) {
            bh[o] = *(const bf16x8*)&Bh[wo + o * 16 + (l & 15)][(l >> 4) * 8];
            bl[o] = *(const bf16x8*)&Bl[wo + o * 16 + (l & 15)][(l >> 4) * 8];
        }
#pragma unroll
        for (int m = 0; m < 4; m++)
#pragma unroll
            for (int o = 0; o < 4; o++) {
                acc[m][o] = __builtin_amdgcn_mfma_f32_16x16x32_bf16(af[m], bh[o], acc[m][o], 0, 0, 0);
                acc[m][o] = __builtin_amdgcn_mfma_f32_16x16x32_bf16(af[m], bl[o], acc[m][o], 0, 0, 0);
            }
        __syncthreads();
    }
#pragma unroll
    for (int m = 0; m < 4; m++) {
        int n = n0 + wn + m * 16 + (l >> 4) * 4;
#pragma unroll
        for (int oi = 0; oi < 4; oi++) {
            int o = o0 + wo + oi * 16 + (l & 15);
            float* dst = qkv_cl + ((size_t)b * HW + n) * TD3 + o;
#pragma unroll
            for (int r = 0; r < 4; r++) dst[(size_t)r * TD3] = acc[m][oi][r];
        }
    }
}

// ---------------- K2: fused depthwise 5x5 + grouped 8x8 pointwise (f32) ----------------
__launch_bounds__(256)
__global__ void k2_dwpw(const float* __restrict__ qkv_cl, const float* __restrict__ w_dw,
                        const float* __restrict__ w_pw, float* __restrict__ agg_cl) {
    __shared__ float wdw_s[8][25];
    __shared__ float wpw_s[8][8];
    int g = blockIdx.x;
    int patch = blockIdx.y;
    int b = blockIdx.z;
    int py = (patch >> 2) * 16, px = (patch & 3) * 16;
    int t = threadIdx.x;
    if (t < 200) wdw_s[t / 25][t % 25] = w_dw[(g * 8 + t / 25) * 25 + t % 25];
    int i2 = t - 200;
    if (i2 >= 0 && i2 < 64) wpw_s[i2 >> 3][i2 & 7] = w_pw[(g * 8 + (i2 >> 3)) * 8 + (i2 & 7)];
    __syncthreads();
    int ly = t >> 4, lx = t & 15;
    int y = py + ly, x = px + lx;
    float dw[8];
#pragma unroll
    for (int i = 0; i < 8; i++) dw[i] = 0.f;
    const float* base = qkv_cl + (size_t)b * HW * TD3 + g * 8;
#pragma unroll
    for (int dy = 0; dy < 5; dy++) {
        int yy = y + dy - 2;
        if (yy < 0 || yy >= 64) continue;
#pragma unroll
        for (int dx = 0; dx < 5; dx++) {
            int xx = x + dx - 2;
            if (xx < 0 || xx >= 64) continue;
            const float* p = base + (size_t)(yy * 64 + xx) * TD3;
            float f[8];
            *(float4*)&f[0] = *(const float4*)p;
            *(float4*)&f[4] = *(const float4*)(p + 4);
#pragma unroll
            for (int i = 0; i < 8; i++) dw[i] += f[i] * wdw_s[i][dy * 5 + dx];
        }
    }
    float ag[8];
#pragma unroll
    for (int o = 0; o < 8; o++) {
        float s = 0.f;
#pragma unroll
        for (int i = 0; i < 8; i++) s += dw[i] * wpw_s[o][i];
        ag[o] = s;
    }
    float* dst = agg_cl + ((size_t)b * HW + y * 64 + x) * TD3 + g * 8;
    float4 o0 = {ag[0], ag[1], ag[2], ag[3]};
    float4 o1 = {ag[4], ag[5], ag[6], ag[7]};
    *(float4*)dst = o0;
    *(float4*)(dst + 4) = o1;
}

// ---------------- K3: linear attention per (b, head), f32 in, bf16 out ----------------
__launch_bounds__(256)
__global__ void k3_attn(const float* __restrict__ qkv_cl, const float* __restrict__ agg_cl,
                        ushort* __restrict__ out_cl) {
    __shared__ float vk_partial[4][72];
    __shared__ float vk_s[72];
    int h = blockIdx.x;
    int b = blockIdx.y;
    const float* src = (h < 32) ? (qkv_cl + (size_t)b * HW * TD3 + h * 24)
                                : (agg_cl + (size_t)b * HW * TD3 + (h - 32) * 24);
    int t = threadIdx.x;
    float vk[9][8];
#pragma unroll
    for (int e = 0; e < 9; e++)
#pragma unroll
        for (int d = 0; d < 8; d++) vk[e][d] = 0.f;

    for (int n = t; n < HW; n += 256) {
        const float* p = src + (size_t)n * TD3;
        float kf[8], vf[8];
        *(float4*)&kf[0] = *(const float4*)(p + 8);
        *(float4*)&kf[4] = *(const float4*)(p + 12);
        *(float4*)&vf[0] = *(const float4*)(p + 16);
        *(float4*)&vf[4] = *(const float4*)(p + 20);
#pragma unroll
        for (int d = 0; d < 8; d++) kf[d] = fmaxf(kf[d], 0.f);
#pragma unroll
        for (int e = 0; e < 8; e++)
#pragma unroll
            for (int d = 0; d < 8; d++) vk[e][d] += vf[e] * kf[d];
#pragma unroll
        for (int d = 0; d < 8; d++) vk[8][d] += kf[d];
    }
#pragma unroll
    for (int e = 0; e < 9; e++)
#pragma unroll
        for (int d = 0; d < 8; d++) {
            float v = vk[e][d];
            for (int off = 32; off > 0; off >>= 1) v += __shfl_xor(v, off);
            vk[e][d] = v;
        }
    int w = t >> 6, l = t & 63;
    if (l == 0) {
#pragma unroll
        for (int e = 0; e < 9; e++)
#pragma unroll
            for (int d = 0; d < 8; d++) vk_partial[w][e * 8 + d] = vk[e][d];
    }
    __syncthreads();
    if (t < 72) vk_s[t] = vk_partial[0][t] + vk_partial[1][t] + vk_partial[2][t] + vk_partial[3][t];
    __syncthreads();
    float vkf[9][8];
#pragma unroll
    for (int e = 0; e < 9; e++)
#pragma unroll
        for (int d = 0; d < 8; d++) vkf[e][d] = vk_s[e * 8 + d];

    ushort* dst = out_cl + (size_t)b * HW * TD2 + h * 8;
    for (int n = t; n < HW; n += 256) {
        const float* p = src + (size_t)n * TD3;
        float qf[8];
        *(float4*)&qf[0] = *(const float4*)p;
        *(float4*)&qf[4] = *(const float4*)(p + 4);
#pragma unroll
        for (int d = 0; d < 8; d++) qf[d] = fmaxf(qf[d], 0.f);
        float o[9];
#pragma unroll
        for (int e = 0; e < 9; e++) {
            float s = 0.f;
#pragma unroll
            for (int d = 0; d < 8; d++) s += vkf[e][d] * qf[d];
            o[e] = s;
        }
        float inv = 1.f / (o[8] + 1e-15f);
        uint4 ov;
        ov.x = pack2(o[0] * inv, o[1] * inv); ov.y = pack2(o[2] * inv, o[3] * inv);
        ov.z = pack2(o[4] * inv, o[5] * inv); ov.w = pack2(o[6] * inv, o[7] * inv);
        *(uint4*)(dst + (size_t)n * TD2) = ov;
    }
}

// ---------------- K4: proj GEMM (split-A on w_proj) + BN + residual ----------------
__launch_bounds__(256)
__global__ void k4_proj(const ushort* __restrict__ out_cl, const float* __restrict__ w_proj,
                        const float* __restrict__ x, const float* __restrict__ gamma,
                        const float* __restrict__ beta, const float* __restrict__ mean,
                        const float* __restrict__ var_, float* __restrict__ out) {
    __shared__ ushort Ah[128][40]; // rows = c (w_proj hi)
    __shared__ ushort Al[128][40]; // rows = c (w_proj lo)
    __shared__ ushort Bld[128][40]; // rows = n (out_cl)
    int b = blockIdx.z;
    int n0 = blockIdx.x * 128;
    int c0 = blockIdx.y * 128;
    int t = threadIdx.x;
    int w = t >> 6, l = t & 63;
    int wc = (w >> 1) * 64, wn = (w & 1) * 64;
    f32x4 acc[4][4];
#pragma unroll
    for (int m = 0; m < 4; m++)
#pragma unroll
        for (int o = 0; o < 4; o++)
#pragma unroll
            for (int r = 0; r < 4; r++) acc[m][o][r] = 0.f;

    const float* Apf = w_proj + (size_t)c0 * TD2;
    const ushort* Bp = out_cl + ((size_t)b * HW + n0) * TD2;

    for (int k0 = 0; k0 < TD2; k0 += 32) {
#pragma unroll
        for (int it = 0; it < 2; it++) {
            int id = t + it * 256;
            int r = id >> 2, q = id & 3;
            const float* src = Apf + (size_t)r * TD2 + k0 + q * 8;
            float f[8];
            *(float4*)&f[0] = *(const float4*)src;
            *(float4*)&f[4] = *(const float4*)(src + 4);
            ushort hi[8]; float lo[8];
#pragma unroll
            for (int j = 0; j < 8; j++) { hi[j] = f2bf(f[j]); lo[j] = f[j] - bf2f(hi[j]); }
            uint4 hv, lv;
            hv.x = (uint)hi[0] | ((uint)hi[1] << 16); hv.y = (uint)hi[2] | ((uint)hi[3] << 16);
            hv.z = (uint)hi[4] | ((uint)hi[5] << 16); hv.w = (uint)hi[6] | ((uint)hi[7] << 16);
            lv.x = pack2(lo[0], lo[1]); lv.y = pack2(lo[2], lo[3]);
            lv.z = pack2(lo[4], lo[5]); lv.w = pack2(lo[6], lo[7]);
            *(uint4*)&Ah[r][q * 8] = hv;
            *(uint4*)&Al[r][q * 8] = lv;
        }
#pragma unroll
        for (int it = 0; it < 2; it++) {
            int id = t + it * 256;
            int r = id >> 2, q = id & 3;
            uint4 v = *(const uint4*)(Bp + (size_t)r * TD2 + k0 + q * 8);
            *(uint4*)&Bld[r][q * 8] = v;
        }
        __syncthreads();
        bf16x8 ah[4], al[4], bf[4];
#pragma unroll
        for (int m = 0; m < 4; m++) {
            ah[m] = *(const bf16x8*)&Ah[wc + m * 16 + (l & 15)][(l >> 4) * 8];
            al[m] = *(const bf16x8*)&Al[wc + m * 16 + (l & 15)][(l >> 4) * 8];
        }
#pragma unroll
        for (int ni = 0; ni < 4; ni++) bf[ni] = *(const bf16x8*)&Bld[wn + ni * 16 + (l & 15)][(l >> 4) * 8];
#pragma unroll
        for (int m = 0; m < 4; m++)
#pragma unroll
            for (int ni = 0; ni < 4; ni++) {
                acc[m][ni] = __builtin_amdgcn_mfma_f32_16x16x32_bf16(ah[m], bf[ni], acc[m][ni], 0, 0, 0);
                acc[m][ni] = __builtin_amdgcn_mfma_f32_16x16x32_bf16(al[m], bf[ni], acc[m][ni], 0, 0, 0);
            }
        __syncthreads();
    }
#pragma unroll
    for (int m = 0; m < 4; m++) {
        int cb = c0 + wc + m * 16 + (l >> 4) * 4;
        float sc[4], mn[4], bt[4];
#pragma unroll
        for (int r = 0; r < 4; r++) {
            sc[r] = gamma[cb + r] * rsqrtf(var_[cb + r] + 1e-5f);
            mn[r] = mean[cb + r];
            bt[r] = beta[cb + r];
        }
#pragma unroll
        for (int ni = 0; ni < 4; ni++) {
            int n = n0 + wn + ni * 16 + (l & 15);
#pragma unroll
            for (int r = 0; r < 4; r++) {
                size_t idx = ((size_t)b * CC + cb + r) * HW + n;
                out[idx] = x[idx] + (acc[m][ni][r] - mn[r]) * sc[r] + bt[r];
            }
        }
    }
}

extern "C" void kernel_launch(void* const* d_in, const int* in_sizes, int n_in,
                              void* d_out, int out_size, void* d_ws, size_t ws_size,
                              hipStream_t stream) {
    const float* x      = (const float*)d_in[0];
    const float* w_qkv  = (const float*)d_in[1];
    const float* w_dw   = (const float*)d_in[2];
    const float* w_pw   = (const float*)d_in[3];
    const float* w_proj = (const float*)d_in[4];
    const float* gamma  = (const float*)d_in[5];
    const float* beta   = (const float*)d_in[6];
    const float* mean   = (const float*)d_in[7];
    const float* var_   = (const float*)d_in[8];
    float* out = (float*)d_out;

    // Per-batch workspace (bytes): x_cl bf16 + qkv f32 + agg f32 + out_cl bf16
    const size_t per_batch = (size_t)HW * CC * 2 + (size_t)HW * TD3 * 4 * 2 + (size_t)HW * TD2 * 2;
    int cb = 16;
    while (cb > 1 && (size_t)cb * per_batch > ws_size) cb >>= 1;

    char* ws = (char*)d_ws;
    ushort* x_cl   = (ushort*)ws;
    float*  qkv_cl = (float*)(ws + (size_t)cb * HW * CC * 2);
    float*  agg_cl = (float*)(ws + (size_t)cb * HW * CC * 2 + (size_t)cb * HW * TD3 * 4);
    ushort* out_cl = (ushort*)(ws + (size_t)cb * HW * CC * 2 + (size_t)cb * HW * TD3 * 8);

    for (int b0 = 0; b0 < BB; b0 += cb) {
        const float* xc = x + (size_t)b0 * CC * HW;
        float* oc = out + (size_t)b0 * CC * HW;
        k0_transpose<<<dim3(64, 4, cb), 256, 0, stream>>>(xc, x_cl);
        k1_qkv<<<dim3(32, 6, cb), 256, 0, stream>>>(x_cl, w_qkv, qkv_cl);
        k2_dwpw<<<dim3(96, 16, cb), 256, 0, stream>>>(qkv_cl, w_dw, w_pw, agg_cl);
        k3_attn<<<dim3(64, cb), 256, 0, stream>>>(qkv_cl, agg_cl, out_cl);
        k4_proj<<<dim3(32, 2, cb), 256, 0, stream>>>(out_cl, w_proj, xc, gamma, beta, mean, var_, oc);
    }
}

// Round 4
// 1349.420 us; speedup vs baseline: 1.0221x; 1.0221x over previous
//
#include <hip/hip_runtime.h>

#define BB 16
#define CC 256
#define HW 4096
#define TD3 768
#define TD2 512

typedef __bf16 bf16x8 __attribute__((ext_vector_type(8)));
typedef float f32x4 __attribute__((ext_vector_type(4)));

__device__ inline ushort f2bf(float f) {
    union { float f; uint u; } v; v.f = f;
    uint u = v.u;
    return (ushort)((u + 0x7FFFu + ((u >> 16) & 1u)) >> 16);
}
__device__ inline float bf2f(ushort h) {
    union { uint u; float f; } v; v.u = ((uint)h) << 16;
    return v.f;
}
__device__ inline uint pack2(float a, float b) {
    return (uint)f2bf(a) | ((uint)f2bf(b) << 16);
}

// ---------------- K0: x (B,C,HW) f32 -> x_cl (B,HW,C) bf16 ----------------
__launch_bounds__(256)
__global__ void k0_transpose(const float* __restrict__ x, ushort* __restrict__ x_cl) {
    __shared__ float tile[64][65];
    int b = blockIdx.z;
    int n0 = blockIdx.x * 64;
    int c0 = blockIdx.y * 64;
    int t = threadIdx.x;
    const float* xp = x + ((size_t)b * CC + c0) * HW + n0;
    int nl = t & 63;
    int cl0 = t >> 6;
#pragma unroll
    for (int i = 0; i < 16; i++) {
        int cl = cl0 + i * 4;
        tile[cl][nl] = xp[(size_t)cl * HW + nl];
    }
    __syncthreads();
#pragma unroll
    for (int it = 0; it < 2; it++) {
        int item = t + it * 256;
        int n = item >> 3;
        int cc = item & 7;
        uint4 o;
        o.x = pack2(tile[cc * 8 + 0][n], tile[cc * 8 + 1][n]);
        o.y = pack2(tile[cc * 8 + 2][n], tile[cc * 8 + 3][n]);
        o.z = pack2(tile[cc * 8 + 4][n], tile[cc * 8 + 5][n]);
        o.w = pack2(tile[cc * 8 + 6][n], tile[cc * 8 + 7][n]);
        *(uint4*)(x_cl + ((size_t)b * HW + n0 + n) * CC + c0 + cc * 8) = o;
    }
}

// ---------------- K1: qkv planes (o, n) f32, split-B GEMM ----------------
__launch_bounds__(256)
__global__ void k1_qkv(const ushort* __restrict__ x_cl, const float* __restrict__ w_qkv,
                       float* __restrict__ qkv_pl) {
    __shared__ ushort Ald[128][40];
    __shared__ ushort Bh[128][40];
    __shared__ ushort Bl[128][40];
    int b = blockIdx.z;
    int n0 = blockIdx.x * 128;
    int o0 = blockIdx.y * 128;
    int t = threadIdx.x;
    int w = t >> 6, l = t & 63;
    int wn = (w >> 1) * 64, wo = (w & 1) * 64;
    f32x4 acc[4][4];
#pragma unroll
    for (int m = 0; m < 4; m++)
#pragma unroll
        for (int o = 0; o < 4; o++)
#pragma unroll
            for (int r = 0; r < 4; r++) acc[m][o][r] = 0.f;

    const ushort* Ap = x_cl + ((size_t)b * HW + n0) * CC;
    const float* Bp = w_qkv + (size_t)o0 * CC;

    for (int k0 = 0; k0 < CC; k0 += 32) {
#pragma unroll
        for (int it = 0; it < 2; it++) {
            int id = t + it * 256;
            int r = id >> 2, q = id & 3;
            uint4 v = *(const uint4*)(Ap + (size_t)r * CC + k0 + q * 8);
            *(uint4*)&Ald[r][q * 8] = v;
        }
#pragma unroll
        for (int it = 0; it < 2; it++) {
            int id = t + it * 256;
            int r = id >> 2, q = id & 3;
            const float* src = Bp + (size_t)r * CC + k0 + q * 8;
            float f[8];
            *(float4*)&f[0] = *(const float4*)src;
            *(float4*)&f[4] = *(const float4*)(src + 4);
            ushort hi[8]; float lo[8];
#pragma unroll
            for (int j = 0; j < 8; j++) { hi[j] = f2bf(f[j]); lo[j] = f[j] - bf2f(hi[j]); }
            uint4 hv, lv;
            hv.x = (uint)hi[0] | ((uint)hi[1] << 16); hv.y = (uint)hi[2] | ((uint)hi[3] << 16);
            hv.z = (uint)hi[4] | ((uint)hi[5] << 16); hv.w = (uint)hi[6] | ((uint)hi[7] << 16);
            lv.x = pack2(lo[0], lo[1]); lv.y = pack2(lo[2], lo[3]);
            lv.z = pack2(lo[4], lo[5]); lv.w = pack2(lo[6], lo[7]);
            *(uint4*)&Bh[r][q * 8] = hv;
            *(uint4*)&Bl[r][q * 8] = lv;
        }
        __syncthreads();
        bf16x8 af[4], bh[4], bl[4];
#pragma unroll
        for (int m = 0; m < 4; m++) af[m] = *(const bf16x8*)&Ald[wn + m * 16 + (l & 15)][(l >> 4) * 8];
#pragma unroll
        for (int o = 0; o < 4; o++) {
            bh[o] = *(const bf16x8*)&Bh[wo + o * 16 + (l & 15)][(l >> 4) * 8];
            bl[o] = *(const bf16x8*)&Bl[wo + o * 16 + (l & 15)][(l >> 4) * 8];
        }
#pragma unroll
        for (int m = 0; m < 4; m++)
#pragma unroll
            for (int o = 0; o < 4; o++) {
                acc[m][o] = __builtin_amdgcn_mfma_f32_16x16x32_bf16(af[m], bh[o], acc[m][o], 0, 0, 0);
                acc[m][o] = __builtin_amdgcn_mfma_f32_16x16x32_bf16(af[m], bl[o], acc[m][o], 0, 0, 0);
            }
        __syncthreads();
    }
    // C-write to planes: reg r is contiguous in n -> float4 stores
#pragma unroll
    for (int m = 0; m < 4; m++) {
        int nb = n0 + wn + m * 16 + (l >> 4) * 4;
#pragma unroll
        for (int oi = 0; oi < 4; oi++) {
            int o = o0 + wo + oi * 16 + (l & 15);
            float4 v4 = {acc[m][oi][0], acc[m][oi][1], acc[m][oi][2], acc[m][oi][3]};
            *(float4*)(qkv_pl + ((size_t)b * TD3 + o) * HW + nb) = v4;
        }
    }
}

// ---------------- K2: plane-layout fused depthwise 5x5 + grouped 8x8 pointwise ----------------
__launch_bounds__(256)
__global__ void k2_dwpw(const float* __restrict__ qkv_pl, const float* __restrict__ w_dw,
                        const float* __restrict__ w_pw, float* __restrict__ agg_pl) {
    __shared__ float lds[8][20][72];   // 8 ch x (16+4 halo rows) x (64 + 4L/4R pad cols)
    __shared__ float wdw_s[8][25];
    __shared__ float wpw_s[8][8];
    int g = blockIdx.x;
    int strip = blockIdx.y;   // 0..3, 16 output rows each
    int b = blockIdx.z;
    int t = threadIdx.x;
    int y0 = strip * 16;
    if (t < 200) wdw_s[t / 25][t % 25] = w_dw[(g * 8 + t / 25) * 25 + t % 25];
    int i2 = t - 200;
    if (i2 >= 0 && i2 < 64) wpw_s[i2 >> 3][i2 & 7] = w_pw[(g * 8 + (i2 >> 3)) * 8 + (i2 & 7)];
    // zero LDS (covers halo rows & pad cols)
    float4 z4 = {0.f, 0.f, 0.f, 0.f};
    float* ldsf = &lds[0][0][0];
#pragma unroll
    for (int i = 0; i < 12; i++) {
        int idx = t + i * 256;
        if (idx < 2880) *(float4*)(ldsf + idx * 4) = z4;
    }
    __syncthreads();
    // stage 8 planes, rows y0-2 .. y0+17, coalesced float4
    const float* src = qkv_pl + ((size_t)b * TD3 + g * 8) * HW;
#pragma unroll
    for (int i = 0; i < 10; i++) {
        int slot = t + i * 256;         // 0..2559 = 8ch * 20rows * 16 float4
        int ch = slot / 320;
        int rem = slot - ch * 320;
        int row = rem >> 4;
        int xq = rem & 15;
        int yy = y0 - 2 + row;
        if (yy >= 0 && yy < 64) {
            float4 v = *(const float4*)(src + (size_t)ch * HW + yy * 64 + xq * 4);
            *(float4*)(&lds[ch][row][4 + xq * 4]) = v;
        }
    }
    __syncthreads();
    float* dstbase = agg_pl + ((size_t)b * TD3 + g * 8) * HW;
#pragma unroll
    for (int i = 0; i < 4; i++) {
        int p = t + i * 256;
        int row = p >> 6;   // 0..15
        int x = p & 63;
        float dw[8];
#pragma unroll
        for (int c = 0; c < 8; c++) dw[c] = 0.f;
#pragma unroll
        for (int dy = 0; dy < 5; dy++)
#pragma unroll
            for (int dx = 0; dx < 5; dx++)
#pragma unroll
                for (int c = 0; c < 8; c++)
                    dw[c] += lds[c][row + dy][2 + x + dx] * wdw_s[c][dy * 5 + dx];
        int n = (y0 + row) * 64 + x;
#pragma unroll
        for (int o = 0; o < 8; o++) {
            float s = 0.f;
#pragma unroll
            for (int c2 = 0; c2 < 8; c2++) s += dw[c2] * wpw_s[o][c2];
            dstbase[(size_t)o * HW + n] = s;
        }
    }
}

// ---------------- K3: linear attention, plane input, channels-last bf16 out ----------------
__launch_bounds__(256)
__global__ void k3_attn(const float* __restrict__ qkv_pl, const float* __restrict__ agg_pl,
                        ushort* __restrict__ out_cl) {
    __shared__ float vk_partial[4][72];
    __shared__ float vk_s[72];
    int h = blockIdx.x;
    int b = blockIdx.y;
    const float* src = (h < 32) ? (qkv_pl + ((size_t)b * TD3 + h * 24) * HW)
                                : (agg_pl + ((size_t)b * TD3 + (h - 32) * 24) * HW);
    const float* kp = src + (size_t)8 * HW;
    const float* vp = src + (size_t)16 * HW;
    int t = threadIdx.x;
    float vk[9][8];
#pragma unroll
    for (int e = 0; e < 9; e++)
#pragma unroll
        for (int d = 0; d < 8; d++) vk[e][d] = 0.f;

#pragma unroll
    for (int it = 0; it < 4; it++) {
        int n4 = (t + it * 256) * 4;
        float4 kf[8], vf[8];
#pragma unroll
        for (int d = 0; d < 8; d++) kf[d] = *(const float4*)(kp + (size_t)d * HW + n4);
#pragma unroll
        for (int e = 0; e < 8; e++) vf[e] = *(const float4*)(vp + (size_t)e * HW + n4);
#pragma unroll
        for (int d = 0; d < 8; d++) {
            kf[d].x = fmaxf(kf[d].x, 0.f); kf[d].y = fmaxf(kf[d].y, 0.f);
            kf[d].z = fmaxf(kf[d].z, 0.f); kf[d].w = fmaxf(kf[d].w, 0.f);
        }
#pragma unroll
        for (int e = 0; e < 8; e++)
#pragma unroll
            for (int d = 0; d < 8; d++)
                vk[e][d] += vf[e].x * kf[d].x + vf[e].y * kf[d].y + vf[e].z * kf[d].z + vf[e].w * kf[d].w;
#pragma unroll
        for (int d = 0; d < 8; d++) vk[8][d] += kf[d].x + kf[d].y + kf[d].z + kf[d].w;
    }
#pragma unroll
    for (int e = 0; e < 9; e++)
#pragma unroll
        for (int d = 0; d < 8; d++) {
            float v = vk[e][d];
            for (int off = 32; off > 0; off >>= 1) v += __shfl_xor(v, off);
            vk[e][d] = v;
        }
    int w = t >> 6, l = t & 63;
    if (l == 0) {
#pragma unroll
        for (int e = 0; e < 9; e++)
#pragma unroll
            for (int d = 0; d < 8; d++) vk_partial[w][e * 8 + d] = vk[e][d];
    }
    __syncthreads();
    if (t < 72) vk_s[t] = vk_partial[0][t] + vk_partial[1][t] + vk_partial[2][t] + vk_partial[3][t];
    __syncthreads();
    float vkf[9][8];
#pragma unroll
    for (int e = 0; e < 9; e++)
#pragma unroll
        for (int d = 0; d < 8; d++) vkf[e][d] = vk_s[e * 8 + d];

    ushort* dst = out_cl + (size_t)b * HW * TD2 + h * 8;
#pragma unroll
    for (int it = 0; it < 4; it++) {
        int n4 = (t + it * 256) * 4;
        float qa[4][8];
#pragma unroll
        for (int d = 0; d < 8; d++) {
            float4 q4 = *(const float4*)(src + (size_t)d * HW + n4);
            qa[0][d] = fmaxf(q4.x, 0.f); qa[1][d] = fmaxf(q4.y, 0.f);
            qa[2][d] = fmaxf(q4.z, 0.f); qa[3][d] = fmaxf(q4.w, 0.f);
        }
#pragma unroll
        for (int j = 0; j < 4; j++) {
            float o[9];
#pragma unroll
            for (int e = 0; e < 9; e++) {
                float s = 0.f;
#pragma unroll
                for (int d = 0; d < 8; d++) s += vkf[e][d] * qa[j][d];
                o[e] = s;
            }
            float inv = 1.f / (o[8] + 1e-15f);
            uint4 ov;
            ov.x = pack2(o[0] * inv, o[1] * inv); ov.y = pack2(o[2] * inv, o[3] * inv);
            ov.z = pack2(o[4] * inv, o[5] * inv); ov.w = pack2(o[6] * inv, o[7] * inv);
            *(uint4*)(dst + (size_t)(n4 + j) * TD2) = ov;
        }
    }
}

// ---------------- K4: proj GEMM (split-A on w_proj) + BN + residual ----------------
__launch_bounds__(256)
__global__ void k4_proj(const ushort* __restrict__ out_cl, const float* __restrict__ w_proj,
                        const float* __restrict__ x, const float* __restrict__ gamma,
                        const float* __restrict__ beta, const float* __restrict__ mean,
                        const float* __restrict__ var_, float* __restrict__ out) {
    __shared__ ushort Ah[128][40];
    __shared__ ushort Al[128][40];
    __shared__ ushort Bld[128][40];
    int b = blockIdx.z;
    int n0 = blockIdx.x * 128;
    int c0 = blockIdx.y * 128;
    int t = threadIdx.x;
    int w = t >> 6, l = t & 63;
    int wc = (w >> 1) * 64, wn = (w & 1) * 64;
    f32x4 acc[4][4];
#pragma unroll
    for (int m = 0; m < 4; m++)
#pragma unroll
        for (int o = 0; o < 4; o++)
#pragma unroll
            for (int r = 0; r < 4; r++) acc[m][o][r] = 0.f;

    const float* Apf = w_proj + (size_t)c0 * TD2;
    const ushort* Bp = out_cl + ((size_t)b * HW + n0) * TD2;

    for (int k0 = 0; k0 < TD2; k0 += 32) {
#pragma unroll
        for (int it = 0; it < 2; it++) {
            int id = t + it * 256;
            int r = id >> 2, q = id & 3;
            const float* src = Apf + (size_t)r * TD2 + k0 + q * 8;
            float f[8];
            *(float4*)&f[0] = *(const float4*)src;
            *(float4*)&f[4] = *(const float4*)(src + 4);
            ushort hi[8]; float lo[8];
#pragma unroll
            for (int j = 0; j < 8; j++) { hi[j] = f2bf(f[j]); lo[j] = f[j] - bf2f(hi[j]); }
            uint4 hv, lv;
            hv.x = (uint)hi[0] | ((uint)hi[1] << 16); hv.y = (uint)hi[2] | ((uint)hi[3] << 16);
            hv.z = (uint)hi[4] | ((uint)hi[5] << 16); hv.w = (uint)hi[6] | ((uint)hi[7] << 16);
            lv.x = pack2(lo[0], lo[1]); lv.y = pack2(lo[2], lo[3]);
            lv.z = pack2(lo[4], lo[5]); lv.w = pack2(lo[6], lo[7]);
            *(uint4*)&Ah[r][q * 8] = hv;
            *(uint4*)&Al[r][q * 8] = lv;
        }
#pragma unroll
        for (int it = 0; it < 2; it++) {
            int id = t + it * 256;
            int r = id >> 2, q = id & 3;
            uint4 v = *(const uint4*)(Bp + (size_t)r * TD2 + k0 + q * 8);
            *(uint4*)&Bld[r][q * 8] = v;
        }
        __syncthreads();
        bf16x8 ah[4], al[4], bf[4];
#pragma unroll
        for (int m = 0; m < 4; m++) {
            ah[m] = *(const bf16x8*)&Ah[wc + m * 16 + (l & 15)][(l >> 4) * 8];
            al[m] = *(const bf16x8*)&Al[wc + m * 16 + (l & 15)][(l >> 4) * 8];
        }
#pragma unroll
        for (int ni = 0; ni < 4; ni++) bf[ni] = *(const bf16x8*)&Bld[wn + ni * 16 + (l & 15)][(l >> 4) * 8];
#pragma unroll
        for (int m = 0; m < 4; m++)
#pragma unroll
            for (int ni = 0; ni < 4; ni++) {
                acc[m][ni] = __builtin_amdgcn_mfma_f32_16x16x32_bf16(ah[m], bf[ni], acc[m][ni], 0, 0, 0);
                acc[m][ni] = __builtin_amdgcn_mfma_f32_16x16x32_bf16(al[m], bf[ni], acc[m][ni], 0, 0, 0);
            }
        __syncthreads();
    }
#pragma unroll
    for (int m = 0; m < 4; m++) {
        int cb = c0 + wc + m * 16 + (l >> 4) * 4;
        float sc[4], mn[4], bt[4];
#pragma unroll
        for (int r = 0; r < 4; r++) {
            sc[r] = gamma[cb + r] * rsqrtf(var_[cb + r] + 1e-5f);
            mn[r] = mean[cb + r];
            bt[r] = beta[cb + r];
        }
#pragma unroll
        for (int ni = 0; ni < 4; ni++) {
            int n = n0 + wn + ni * 16 + (l & 15);
#pragma unroll
            for (int r = 0; r < 4; r++) {
                size_t idx = ((size_t)b * CC + cb + r) * HW + n;
                out[idx] = x[idx] + (acc[m][ni][r] - mn[r]) * sc[r] + bt[r];
            }
        }
    }
}

extern "C" void kernel_launch(void* const* d_in, const int* in_sizes, int n_in,
                              void* d_out, int out_size, void* d_ws, size_t ws_size,
                              hipStream_t stream) {
    const float* x      = (const float*)d_in[0];
    const float* w_qkv  = (const float*)d_in[1];
    const float* w_dw   = (const float*)d_in[2];
    const float* w_pw   = (const float*)d_in[3];
    const float* w_proj = (const float*)d_in[4];
    const float* gamma  = (const float*)d_in[5];
    const float* beta   = (const float*)d_in[6];
    const float* mean   = (const float*)d_in[7];
    const float* var_   = (const float*)d_in[8];
    float* out = (float*)d_out;

    // Per-batch workspace (bytes): x_cl bf16 + qkv f32 planes + agg f32 planes + out_cl bf16
    const size_t per_batch = (size_t)HW * CC * 2 + (size_t)HW * TD3 * 4 * 2 + (size_t)HW * TD2 * 2;
    int cb = 16;
    while (cb > 1 && (size_t)cb * per_batch > ws_size) cb >>= 1;

    char* ws = (char*)d_ws;
    ushort* x_cl   = (ushort*)ws;
    float*  qkv_pl = (float*)(ws + (size_t)cb * HW * CC * 2);
    float*  agg_pl = (float*)(ws + (size_t)cb * HW * CC * 2 + (size_t)cb * HW * TD3 * 4);
    ushort* out_cl = (ushort*)(ws + (size_t)cb * HW * CC * 2 + (size_t)cb * HW * TD3 * 8);

    for (int b0 = 0; b0 < BB; b0 += cb) {
        const float* xc = x + (size_t)b0 * CC * HW;
        float* oc = out + (size_t)b0 * CC * HW;
        k0_transpose<<<dim3(64, 4, cb), 256, 0, stream>>>(xc, x_cl);
        k1_qkv<<<dim3(32, 6, cb), 256, 0, stream>>>(x_cl, w_qkv, qkv_pl);
        k2_dwpw<<<dim3(96, 4, cb), 256, 0, stream>>>(qkv_pl, w_dw, w_pw, agg_pl);
        k3_attn<<<dim3(64, cb), 256, 0, stream>>>(qkv_pl, agg_pl, out_cl);
        k4_proj<<<dim3(32, 2, cb), 256, 0, stream>>>(out_cl, w_proj, xc, gamma, beta, mean, var_, oc);
    }
}

// Round 5
// 746.267 us; speedup vs baseline: 1.8482x; 1.8082x over previous
//
#include <hip/hip_runtime.h>

#define BB 16
#define CC 256
#define HW 4096
#define TD3 768
#define TD2 512

typedef __bf16 bf16x8 __attribute__((ext_vector_type(8)));
typedef float f32x4 __attribute__((ext_vector_type(4)));

__device__ inline ushort f2bf(float f) {
    union { float f; uint u; } v; v.f = f;
    uint u = v.u;
    return (ushort)((u + 0x7FFFu + ((u >> 16) & 1u)) >> 16);
}
__device__ inline float bf2f(ushort h) {
    union { uint u; float f; } v; v.u = ((uint)h) << 16;
    return v.f;
}
__device__ inline uint pack2(float a, float b) {
    return (uint)f2bf(a) | ((uint)f2bf(b) << 16);
}

// ---------------- K0: x (B,C,HW) f32 -> x_cl (B,HW,C) bf16 ----------------
__launch_bounds__(256)
__global__ void k0_transpose(const float* __restrict__ x, ushort* __restrict__ x_cl) {
    __shared__ float tile[64][65];
    int b = blockIdx.z;
    int n0 = blockIdx.x * 64;
    int c0 = blockIdx.y * 64;
    int t = threadIdx.x;
    const float* xp = x + ((size_t)b * CC + c0) * HW + n0;
    int nl = t & 63;
    int cl0 = t >> 6;
#pragma unroll
    for (int i = 0; i < 16; i++) {
        int cl = cl0 + i * 4;
        tile[cl][nl] = xp[(size_t)cl * HW + nl];
    }
    __syncthreads();
#pragma unroll
    for (int it = 0; it < 2; it++) {
        int item = t + it * 256;
        int n = item >> 3;
        int cc = item & 7;
        uint4 o;
        o.x = pack2(tile[cc * 8 + 0][n], tile[cc * 8 + 1][n]);
        o.y = pack2(tile[cc * 8 + 2][n], tile[cc * 8 + 3][n]);
        o.z = pack2(tile[cc * 8 + 4][n], tile[cc * 8 + 5][n]);
        o.w = pack2(tile[cc * 8 + 6][n], tile[cc * 8 + 7][n]);
        *(uint4*)(x_cl + ((size_t)b * HW + n0 + n) * CC + c0 + cc * 8) = o;
    }
}

// ---------------- K1: qkv planes (o, n) f32, split-B GEMM ----------------
__launch_bounds__(256)
__global__ void k1_qkv(const ushort* __restrict__ x_cl, const float* __restrict__ w_qkv,
                       float* __restrict__ qkv_pl) {
    __shared__ ushort Ald[128][40];
    __shared__ ushort Bh[128][40];
    __shared__ ushort Bl[128][40];
    int b = blockIdx.z;
    int n0 = blockIdx.x * 128;
    int o0 = blockIdx.y * 128;
    int t = threadIdx.x;
    int w = t >> 6, l = t & 63;
    int wn = (w >> 1) * 64, wo = (w & 1) * 64;
    f32x4 acc[4][4];
#pragma unroll
    for (int m = 0; m < 4; m++)
#pragma unroll
        for (int o = 0; o < 4; o++)
#pragma unroll
            for (int r = 0; r < 4; r++) acc[m][o][r] = 0.f;

    const ushort* Ap = x_cl + ((size_t)b * HW + n0) * CC;
    const float* Bp = w_qkv + (size_t)o0 * CC;

    for (int k0 = 0; k0 < CC; k0 += 32) {
#pragma unroll
        for (int it = 0; it < 2; it++) {
            int id = t + it * 256;
            int r = id >> 2, q = id & 3;
            uint4 v = *(const uint4*)(Ap + (size_t)r * CC + k0 + q * 8);
            *(uint4*)&Ald[r][q * 8] = v;
        }
#pragma unroll
        for (int it = 0; it < 2; it++) {
            int id = t + it * 256;
            int r = id >> 2, q = id & 3;
            const float* src = Bp + (size_t)r * CC + k0 + q * 8;
            float f[8];
            *(float4*)&f[0] = *(const float4*)src;
            *(float4*)&f[4] = *(const float4*)(src + 4);
            ushort hi[8]; float lo[8];
#pragma unroll
            for (int j = 0; j < 8; j++) { hi[j] = f2bf(f[j]); lo[j] = f[j] - bf2f(hi[j]); }
            uint4 hv, lv;
            hv.x = (uint)hi[0] | ((uint)hi[1] << 16); hv.y = (uint)hi[2] | ((uint)hi[3] << 16);
            hv.z = (uint)hi[4] | ((uint)hi[5] << 16); hv.w = (uint)hi[6] | ((uint)hi[7] << 16);
            lv.x = pack2(lo[0], lo[1]); lv.y = pack2(lo[2], lo[3]);
            lv.z = pack2(lo[4], lo[5]); lv.w = pack2(lo[6], lo[7]);
            *(uint4*)&Bh[r][q * 8] = hv;
            *(uint4*)&Bl[r][q * 8] = lv;
        }
        __syncthreads();
        bf16x8 af[4], bh[4], bl[4];
#pragma unroll
        for (int m = 0; m < 4; m++) af[m] = *(const bf16x8*)&Ald[wn + m * 16 + (l & 15)][(l >> 4) * 8];
#pragma unroll
        for (int o = 0; o < 4; o++) {
            bh[o] = *(const bf16x8*)&Bh[wo + o * 16 + (l & 15)][(l >> 4) * 8];
            bl[o] = *(const bf16x8*)&Bl[wo + o * 16 + (l & 15)][(l >> 4) * 8];
        }
#pragma unroll
        for (int m = 0; m < 4; m++)
#pragma unroll
            for (int o = 0; o < 4; o++) {
                acc[m][o] = __builtin_amdgcn_mfma_f32_16x16x32_bf16(af[m], bh[o], acc[m][o], 0, 0, 0);
                acc[m][o] = __builtin_amdgcn_mfma_f32_16x16x32_bf16(af[m], bl[o], acc[m][o], 0, 0, 0);
            }
        __syncthreads();
    }
    // C-write to planes: reg r is contiguous in n -> float4 stores
#pragma unroll
    for (int m = 0; m < 4; m++) {
        int nb = n0 + wn + m * 16 + (l >> 4) * 4;
#pragma unroll
        for (int oi = 0; oi < 4; oi++) {
            int o = o0 + wo + oi * 16 + (l & 15);
            float4 v4 = {acc[m][oi][0], acc[m][oi][1], acc[m][oi][2], acc[m][oi][3]};
            *(float4*)(qkv_pl + ((size_t)b * TD3 + o) * HW + nb) = v4;
        }
    }
}

// ---------------- K2: plane-layout fused depthwise 5x5 + grouped 8x8 pointwise ----------------
// strip = 8 output rows; LDS tile 8ch x 12rows x 72cols f32 = 27.6 KB; 2 px/thread sequential.
__launch_bounds__(256)
__global__ void k2_dwpw(const float* __restrict__ qkv_pl, const float* __restrict__ w_dw,
                        const float* __restrict__ w_pw, float* __restrict__ agg_pl) {
    __shared__ float lds[8][12][72];
    __shared__ float wdw_s[8][25];
    __shared__ float wpw_s[8][8];
    int g = blockIdx.x;
    int strip = blockIdx.y;   // 0..7, 8 output rows each
    int b = blockIdx.z;
    int t = threadIdx.x;
    int y0 = strip * 8;
    if (t < 200) wdw_s[t / 25][t % 25] = w_dw[(g * 8 + t / 25) * 25 + t % 25];
    int i2 = t - 200;
    if (i2 >= 0 && i2 < 64) wpw_s[i2 >> 3][i2 & 7] = w_pw[(g * 8 + (i2 >> 3)) * 8 + (i2 & 7)];
    // zero LDS tile (halo rows & pad cols): 8*12*72 = 6912 floats = 1728 float4
    float4 z4 = {0.f, 0.f, 0.f, 0.f};
    float* ldsf = &lds[0][0][0];
#pragma unroll
    for (int i = 0; i < 7; i++) {
        int idx = t + i * 256;
        if (idx < 1728) *(float4*)(ldsf + idx * 4) = z4;
    }
    __syncthreads();
    // stage 8 planes, rows y0-2 .. y0+9, coalesced float4: 8ch*12rows*16q = 1536 slots
    const float* src = qkv_pl + ((size_t)b * TD3 + g * 8) * HW;
#pragma unroll
    for (int i = 0; i < 6; i++) {
        int slot = t + i * 256;
        int ch = slot / 192;
        int rem = slot - ch * 192;
        int row = rem >> 4;
        int xq = rem & 15;
        int yy = y0 - 2 + row;
        if (yy >= 0 && yy < 64) {
            float4 v = *(const float4*)(src + (size_t)ch * HW + yy * 64 + xq * 4);
            *(float4*)(&lds[ch][row][4 + xq * 4]) = v;
        }
    }
    __syncthreads();
    float* dstbase = agg_pl + ((size_t)b * TD3 + g * 8) * HW;
#pragma unroll 1
    for (int i = 0; i < 2; i++) {
        int p = t + i * 256;
        int row = p >> 6;   // 0..7
        int x = p & 63;
        float dw[8];
#pragma unroll
        for (int c = 0; c < 8; c++) dw[c] = 0.f;
#pragma unroll
        for (int dy = 0; dy < 5; dy++)
#pragma unroll
            for (int dx = 0; dx < 5; dx++)
#pragma unroll
                for (int c = 0; c < 8; c++)
                    dw[c] += lds[c][row + dy][2 + x + dx] * wdw_s[c][dy * 5 + dx];
        int n = (y0 + row) * 64 + x;
#pragma unroll
        for (int o = 0; o < 8; o++) {
            float s = 0.f;
#pragma unroll
            for (int c2 = 0; c2 < 8; c2++) s += dw[c2] * wpw_s[o][c2];
            dstbase[(size_t)o * HW + n] = s;
        }
    }
}

// ---------------- K3: linear attention, plane input, channels-last bf16 out ----------------
__launch_bounds__(256)
__global__ void k3_attn(const float* __restrict__ qkv_pl, const float* __restrict__ agg_pl,
                        ushort* __restrict__ out_cl) {
    __shared__ float vk_partial[4][72];
    __shared__ float vk_s[72];
    int h = blockIdx.x;
    int b = blockIdx.y;
    const float* src = (h < 32) ? (qkv_pl + ((size_t)b * TD3 + h * 24) * HW)
                                : (agg_pl + ((size_t)b * TD3 + (h - 32) * 24) * HW);
    const float* kp = src + (size_t)8 * HW;
    const float* vp = src + (size_t)16 * HW;
    int t = threadIdx.x;
    float vk[9][8];
#pragma unroll
    for (int e = 0; e < 9; e++)
#pragma unroll
        for (int d = 0; d < 8; d++) vk[e][d] = 0.f;

#pragma unroll
    for (int it = 0; it < 4; it++) {
        int n4 = (t + it * 256) * 4;
        float4 kf[8], vf[8];
#pragma unroll
        for (int d = 0; d < 8; d++) kf[d] = *(const float4*)(kp + (size_t)d * HW + n4);
#pragma unroll
        for (int e = 0; e < 8; e++) vf[e] = *(const float4*)(vp + (size_t)e * HW + n4);
#pragma unroll
        for (int d = 0; d < 8; d++) {
            kf[d].x = fmaxf(kf[d].x, 0.f); kf[d].y = fmaxf(kf[d].y, 0.f);
            kf[d].z = fmaxf(kf[d].z, 0.f); kf[d].w = fmaxf(kf[d].w, 0.f);
        }
#pragma unroll
        for (int e = 0; e < 8; e++)
#pragma unroll
            for (int d = 0; d < 8; d++)
                vk[e][d] += vf[e].x * kf[d].x + vf[e].y * kf[d].y + vf[e].z * kf[d].z + vf[e].w * kf[d].w;
#pragma unroll
        for (int d = 0; d < 8; d++) vk[8][d] += kf[d].x + kf[d].y + kf[d].z + kf[d].w;
    }
#pragma unroll
    for (int e = 0; e < 9; e++)
#pragma unroll
        for (int d = 0; d < 8; d++) {
            float v = vk[e][d];
            for (int off = 32; off > 0; off >>= 1) v += __shfl_xor(v, off);
            vk[e][d] = v;
        }
    int w = t >> 6, l = t & 63;
    if (l == 0) {
#pragma unroll
        for (int e = 0; e < 9; e++)
#pragma unroll
            for (int d = 0; d < 8; d++) vk_partial[w][e * 8 + d] = vk[e][d];
    }
    __syncthreads();
    if (t < 72) vk_s[t] = vk_partial[0][t] + vk_partial[1][t] + vk_partial[2][t] + vk_partial[3][t];
    __syncthreads();
    float vkf[9][8];
#pragma unroll
    for (int e = 0; e < 9; e++)
#pragma unroll
        for (int d = 0; d < 8; d++) vkf[e][d] = vk_s[e * 8 + d];

    ushort* dst = out_cl + (size_t)b * HW * TD2 + h * 8;
#pragma unroll
    for (int it = 0; it < 4; it++) {
        int n4 = (t + it * 256) * 4;
        float qa[4][8];
#pragma unroll
        for (int d = 0; d < 8; d++) {
            float4 q4 = *(const float4*)(src + (size_t)d * HW + n4);
            qa[0][d] = fmaxf(q4.x, 0.f); qa[1][d] = fmaxf(q4.y, 0.f);
            qa[2][d] = fmaxf(q4.z, 0.f); qa[3][d] = fmaxf(q4.w, 0.f);
        }
#pragma unroll
        for (int j = 0; j < 4; j++) {
            float o[9];
#pragma unroll
            for (int e = 0; e < 9; e++) {
                float s = 0.f;
#pragma unroll
                for (int d = 0; d < 8; d++) s += vkf[e][d] * qa[j][d];
                o[e] = s;
            }
            float inv = 1.f / (o[8] + 1e-15f);
            uint4 ov;
            ov.x = pack2(o[0] * inv, o[1] * inv); ov.y = pack2(o[2] * inv, o[3] * inv);
            ov.z = pack2(o[4] * inv, o[5] * inv); ov.w = pack2(o[6] * inv, o[7] * inv);
            *(uint4*)(dst + (size_t)(n4 + j) * TD2) = ov;
        }
    }
}

// ---------------- K4: proj GEMM (split-A on w_proj) + BN + residual ----------------
__launch_bounds__(256)
__global__ void k4_proj(const ushort* __restrict__ out_cl, const float* __restrict__ w_proj,
                        const float* __restrict__ x, const float* __restrict__ gamma,
                        const float* __restrict__ beta, const float* __restrict__ mean,
                        const float* __restrict__ var_, float* __restrict__ out) {
    __shared__ ushort Ah[128][40];
    __shared__ ushort Al[128][40];
    __shared__ ushort Bld[128][40];
    int b = blockIdx.z;
    int n0 = blockIdx.x * 128;
    int c0 = blockIdx.y * 128;
    int t = threadIdx.x;
    int w = t >> 6, l = t & 63;
    int wc = (w >> 1) * 64, wn = (w & 1) * 64;
    f32x4 acc[4][4];
#pragma unroll
    for (int m = 0; m < 4; m++)
#pragma unroll
        for (int o = 0; o < 4; o++)
#pragma unroll
            for (int r = 0; r < 4; r++) acc[m][o][r] = 0.f;

    const float* Apf = w_proj + (size_t)c0 * TD2;
    const ushort* Bp = out_cl + ((size_t)b * HW + n0) * TD2;

    for (int k0 = 0; k0 < TD2; k0 += 32) {
#pragma unroll
        for (int it = 0; it < 2; it++) {
            int id = t + it * 256;
            int r = id >> 2, q = id & 3;
            const float* src = Apf + (size_t)r * TD2 + k0 + q * 8;
            float f[8];
            *(float4*)&f[0] = *(const float4*)src;
            *(float4*)&f[4] = *(const float4*)(src + 4);
            ushort hi[8]; float lo[8];
#pragma unroll
            for (int j = 0; j < 8; j++) { hi[j] = f2bf(f[j]); lo[j] = f[j] - bf2f(hi[j]); }
            uint4 hv, lv;
            hv.x = (uint)hi[0] | ((uint)hi[1] << 16); hv.y = (uint)hi[2] | ((uint)hi[3] << 16);
            hv.z = (uint)hi[4] | ((uint)hi[5] << 16); hv.w = (uint)hi[6] | ((uint)hi[7] << 16);
            lv.x = pack2(lo[0], lo[1]); lv.y = pack2(lo[2], lo[3]);
            lv.z = pack2(lo[4], lo[5]); lv.w = pack2(lo[6], lo[7]);
            *(uint4*)&Ah[r][q * 8] = hv;
            *(uint4*)&Al[r][q * 8] = lv;
        }
#pragma unroll
        for (int it = 0; it < 2; it++) {
            int id = t + it * 256;
            int r = id >> 2, q = id & 3;
            uint4 v = *(const uint4*)(Bp + (size_t)r * TD2 + k0 + q * 8);
            *(uint4*)&Bld[r][q * 8] = v;
        }
        __syncthreads();
        bf16x8 ah[4], al[4], bf[4];
#pragma unroll
        for (int m = 0; m < 4; m++) {
            ah[m] = *(const bf16x8*)&Ah[wc + m * 16 + (l & 15)][(l >> 4) * 8];
            al[m] = *(const bf16x8*)&Al[wc + m * 16 + (l & 15)][(l >> 4) * 8];
        }
#pragma unroll
        for (int ni = 0; ni < 4; ni++) bf[ni] = *(const bf16x8*)&Bld[wn + ni * 16 + (l & 15)][(l >> 4) * 8];
#pragma unroll
        for (int m = 0; m < 4; m++)
#pragma unroll
            for (int ni = 0; ni < 4; ni++) {
                acc[m][ni] = __builtin_amdgcn_mfma_f32_16x16x32_bf16(ah[m], bf[ni], acc[m][ni], 0, 0, 0);
                acc[m][ni] = __builtin_amdgcn_mfma_f32_16x16x32_bf16(al[m], bf[ni], acc[m][ni], 0, 0, 0);
            }
        __syncthreads();
    }
#pragma unroll
    for (int m = 0; m < 4; m++) {
        int cb = c0 + wc + m * 16 + (l >> 4) * 4;
        float sc[4], mn[4], bt[4];
#pragma unroll
        for (int r = 0; r < 4; r++) {
            sc[r] = gamma[cb + r] * rsqrtf(var_[cb + r] + 1e-5f);
            mn[r] = mean[cb + r];
            bt[r] = beta[cb + r];
        }
#pragma unroll
        for (int ni = 0; ni < 4; ni++) {
            int n = n0 + wn + ni * 16 + (l & 15);
#pragma unroll
            for (int r = 0; r < 4; r++) {
                size_t idx = ((size_t)b * CC + cb + r) * HW + n;
                out[idx] = x[idx] + (acc[m][ni][r] - mn[r]) * sc[r] + bt[r];
            }
        }
    }
}

extern "C" void kernel_launch(void* const* d_in, const int* in_sizes, int n_in,
                              void* d_out, int out_size, void* d_ws, size_t ws_size,
                              hipStream_t stream) {
    const float* x      = (const float*)d_in[0];
    const float* w_qkv  = (const float*)d_in[1];
    const float* w_dw   = (const float*)d_in[2];
    const float* w_pw   = (const float*)d_in[3];
    const float* w_proj = (const float*)d_in[4];
    const float* gamma  = (const float*)d_in[5];
    const float* beta   = (const float*)d_in[6];
    const float* mean   = (const float*)d_in[7];
    const float* var_   = (const float*)d_in[8];
    float* out = (float*)d_out;

    // Per-batch workspace (bytes): x_cl bf16 + qkv f32 planes + agg f32 planes + out_cl bf16
    const size_t per_batch = (size_t)HW * CC * 2 + (size_t)HW * TD3 * 4 * 2 + (size_t)HW * TD2 * 2;
    int cb = 16;
    while (cb > 1 && (size_t)cb * per_batch > ws_size) cb >>= 1;

    char* ws = (char*)d_ws;
    ushort* x_cl   = (ushort*)ws;
    float*  qkv_pl = (float*)(ws + (size_t)cb * HW * CC * 2);
    float*  agg_pl = (float*)(ws + (size_t)cb * HW * CC * 2 + (size_t)cb * HW * TD3 * 4);
    ushort* out_cl = (ushort*)(ws + (size_t)cb * HW * CC * 2 + (size_t)cb * HW * TD3 * 8);

    for (int b0 = 0; b0 < BB; b0 += cb) {
        const float* xc = x + (size_t)b0 * CC * HW;
        float* oc = out + (size_t)b0 * CC * HW;
        k0_transpose<<<dim3(64, 4, cb), 256, 0, stream>>>(xc, x_cl);
        k1_qkv<<<dim3(32, 6, cb), 256, 0, stream>>>(x_cl, w_qkv, qkv_pl);
        k2_dwpw<<<dim3(96, 8, cb), 256, 0, stream>>>(qkv_pl, w_dw, w_pw, agg_pl);
        k3_attn<<<dim3(64, cb), 256, 0, stream>>>(qkv_pl, agg_pl, out_cl);
        k4_proj<<<dim3(32, 2, cb), 256, 0, stream>>>(out_cl, w_proj, xc, gamma, beta, mean, var_, oc);
    }
}

// Round 6
// 454.132 us; speedup vs baseline: 3.0371x; 1.6433x over previous
//
#include <hip/hip_runtime.h>

#define BB 16
#define CC 256
#define HW 4096
#define TD3 768
#define TD2 512

typedef __bf16 bf16x8 __attribute__((ext_vector_type(8)));
typedef float f32x4 __attribute__((ext_vector_type(4)));

__device__ inline ushort f2bf(float f) {
    union { float f; uint u; } v; v.f = f;
    uint u = v.u;
    return (ushort)((u + 0x7FFFu + ((u >> 16) & 1u)) >> 16);
}
__device__ inline float bf2f(ushort h) {
    union { uint u; float f; } v; v.u = ((uint)h) << 16;
    return v.f;
}
__device__ inline uint pack2(float a, float b) {
    return (uint)f2bf(a) | ((uint)f2bf(b) << 16);
}

// ---------------- K0: x (B,C,HW) f32 -> x_cl (B,HW,C) bf16 ----------------
__launch_bounds__(256)
__global__ void k0_transpose(const float* __restrict__ x, ushort* __restrict__ x_cl) {
    __shared__ float tile[64][65];
    int b = blockIdx.z;
    int n0 = blockIdx.x * 64;
    int c0 = blockIdx.y * 64;
    int t = threadIdx.x;
    const float* xp = x + ((size_t)b * CC + c0) * HW + n0;
    int nl = t & 63;
    int cl0 = t >> 6;
#pragma unroll
    for (int i = 0; i < 16; i++) {
        int cl = cl0 + i * 4;
        tile[cl][nl] = xp[(size_t)cl * HW + nl];
    }
    __syncthreads();
#pragma unroll
    for (int it = 0; it < 2; it++) {
        int item = t + it * 256;
        int n = item >> 3;
        int cc = item & 7;
        uint4 o;
        o.x = pack2(tile[cc * 8 + 0][n], tile[cc * 8 + 1][n]);
        o.y = pack2(tile[cc * 8 + 2][n], tile[cc * 8 + 3][n]);
        o.z = pack2(tile[cc * 8 + 4][n], tile[cc * 8 + 5][n]);
        o.w = pack2(tile[cc * 8 + 6][n], tile[cc * 8 + 7][n]);
        *(uint4*)(x_cl + ((size_t)b * HW + n0 + n) * CC + c0 + cc * 8) = o;
    }
}

// ---------------- K1: qkv planes (o, n) f32, split-B GEMM ----------------
__launch_bounds__(256)
__global__ void k1_qkv(const ushort* __restrict__ x_cl, const float* __restrict__ w_qkv,
                       float* __restrict__ qkv_pl) {
    __shared__ ushort Ald[128][40];
    __shared__ ushort Bh[128][40];
    __shared__ ushort Bl[128][40];
    int b = blockIdx.z;
    int n0 = blockIdx.x * 128;
    int o0 = blockIdx.y * 128;
    int t = threadIdx.x;
    int w = t >> 6, l = t & 63;
    int wn = (w >> 1) * 64, wo = (w & 1) * 64;
    f32x4 acc[4][4];
#pragma unroll
    for (int m = 0; m < 4; m++)
#pragma unroll
        for (int o = 0; o < 4; o++)
#pragma unroll
            for (int r = 0; r < 4; r++) acc[m][o][r] = 0.f;

    const ushort* Ap = x_cl + ((size_t)b * HW + n0) * CC;
    const float* Bp = w_qkv + (size_t)o0 * CC;

    for (int k0 = 0; k0 < CC; k0 += 32) {
#pragma unroll
        for (int it = 0; it < 2; it++) {
            int id = t + it * 256;
            int r = id >> 2, q = id & 3;
            uint4 v = *(const uint4*)(Ap + (size_t)r * CC + k0 + q * 8);
            *(uint4*)&Ald[r][q * 8] = v;
        }
#pragma unroll
        for (int it = 0; it < 2; it++) {
            int id = t + it * 256;
            int r = id >> 2, q = id & 3;
            const float* src = Bp + (size_t)r * CC + k0 + q * 8;
            float f[8];
            *(float4*)&f[0] = *(const float4*)src;
            *(float4*)&f[4] = *(const float4*)(src + 4);
            ushort hi[8]; float lo[8];
#pragma unroll
            for (int j = 0; j < 8; j++) { hi[j] = f2bf(f[j]); lo[j] = f[j] - bf2f(hi[j]); }
            uint4 hv, lv;
            hv.x = (uint)hi[0] | ((uint)hi[1] << 16); hv.y = (uint)hi[2] | ((uint)hi[3] << 16);
            hv.z = (uint)hi[4] | ((uint)hi[5] << 16); hv.w = (uint)hi[6] | ((uint)hi[7] << 16);
            lv.x = pack2(lo[0], lo[1]); lv.y = pack2(lo[2], lo[3]);
            lv.z = pack2(lo[4], lo[5]); lv.w = pack2(lo[6], lo[7]);
            *(uint4*)&Bh[r][q * 8] = hv;
            *(uint4*)&Bl[r][q * 8] = lv;
        }
        __syncthreads();
        bf16x8 af[4], bh[4], bl[4];
#pragma unroll
        for (int m = 0; m < 4; m++) af[m] = *(const bf16x8*)&Ald[wn + m * 16 + (l & 15)][(l >> 4) * 8];
#pragma unroll
        for (int o = 0; o < 4; o++) {
            bh[o] = *(const bf16x8*)&Bh[wo + o * 16 + (l & 15)][(l >> 4) * 8];
            bl[o] = *(const bf16x8*)&Bl[wo + o * 16 + (l & 15)][(l >> 4) * 8];
        }
#pragma unroll
        for (int m = 0; m < 4; m++)
#pragma unroll
            for (int o = 0; o < 4; o++) {
                acc[m][o] = __builtin_amdgcn_mfma_f32_16x16x32_bf16(af[m], bh[o], acc[m][o], 0, 0, 0);
                acc[m][o] = __builtin_amdgcn_mfma_f32_16x16x32_bf16(af[m], bl[o], acc[m][o], 0, 0, 0);
            }
        __syncthreads();
    }
    // C-write to planes: reg r is contiguous in n -> float4 stores
#pragma unroll
    for (int m = 0; m < 4; m++) {
        int nb = n0 + wn + m * 16 + (l >> 4) * 4;
#pragma unroll
        for (int oi = 0; oi < 4; oi++) {
            int o = o0 + wo + oi * 16 + (l & 15);
            float4 v4 = {acc[m][oi][0], acc[m][oi][1], acc[m][oi][2], acc[m][oi][3]};
            *(float4*)(qkv_pl + ((size_t)b * TD3 + o) * HW + nb) = v4;
        }
    }
}

// ---------------- K2: plane-layout fused depthwise 5x5 + grouped 8x8 pointwise ----------------
// strip = 16 rows; LDS tile 8ch x 20rows x 72cols f32 (left pad 2); 4 px/thread, 1 row.
// Windows read as 2 aligned ds_read_b128; weights via uniform (scalar) global loads.
__launch_bounds__(256)
__global__ void k2_dwpw(const float* __restrict__ qkv_pl, const float* __restrict__ w_dw,
                        const float* __restrict__ w_pw, float* __restrict__ agg_pl) {
    __shared__ __align__(16) float lds[8][20][72];
    int g = blockIdx.x;
    int strip = blockIdx.y;   // 0..3, 16 output rows each
    int b = blockIdx.z;
    int t = threadIdx.x;
    int y0 = strip * 16;
    const float* wg  = w_dw + (size_t)g * 200;  // 8 ch x 25 taps, block-uniform
    const float* wpg = w_pw + (size_t)g * 64;   // 8x8, block-uniform

    // zero LDS tile (halo rows & pad cols): 8*20*72 = 11520 floats = 2880 float4
    float4 z4 = {0.f, 0.f, 0.f, 0.f};
    float* ldsf = &lds[0][0][0];
#pragma unroll
    for (int i = 0; i < 12; i++) {
        int idx = t + i * 256;
        if (idx < 2880) *(float4*)(ldsf + idx * 4) = z4;
    }
    __syncthreads();
    // stage rows y0-2 .. y0+17: 8ch * 20rows * 16quads = 2560 slots, 10 per thread
    const float* src = qkv_pl + ((size_t)b * TD3 + g * 8) * HW;
#pragma unroll
    for (int i = 0; i < 10; i++) {
        int slot = t + i * 256;
        int ch = slot / 320;
        int rem = slot - ch * 320;
        int row = rem >> 4;
        int q = rem & 15;
        int yy = y0 - 2 + row;
        if (yy >= 0 && yy < 64) {
            float4 v = *(const float4*)(src + (size_t)ch * HW + yy * 64 + q * 4);
            // dest idx 2+4q -> byte 8+16q: 8-aligned, use two float2 writes
            float2 lo2 = {v.x, v.y}, hi2 = {v.z, v.w};
            *(float2*)(&lds[ch][row][2 + 4 * q]) = lo2;
            *(float2*)(&lds[ch][row][4 + 4 * q]) = hi2;
        }
    }
    __syncthreads();

    int seg = t & 15, row = t >> 4;   // 16 segs x 16 rows
    float dw[8][4];
#pragma unroll
    for (int c = 0; c < 8; c++)
#pragma unroll
        for (int j = 0; j < 4; j++) dw[c][j] = 0.f;

#pragma unroll
    for (int c = 0; c < 8; c++) {
#pragma unroll
        for (int dy = 0; dy < 5; dy++) {
            float win[8];
            *(float4*)&win[0] = *(const float4*)&lds[c][row + dy][4 * seg];     // x = 4s-2..4s+1
            *(float4*)&win[4] = *(const float4*)&lds[c][row + dy][4 * seg + 4]; // x = 4s+2..4s+5
#pragma unroll
            for (int dx = 0; dx < 5; dx++) {
                float wv = wg[c * 25 + dy * 5 + dx];
#pragma unroll
                for (int j = 0; j < 4; j++) dw[c][j] += win[dx + j] * wv;
            }
        }
    }
    float* dstbase = agg_pl + ((size_t)b * TD3 + g * 8) * HW;
    int n = (y0 + row) * 64 + seg * 4;
#pragma unroll
    for (int o = 0; o < 8; o++) {
        float s0 = 0.f, s1 = 0.f, s2 = 0.f, s3 = 0.f;
#pragma unroll
        for (int c = 0; c < 8; c++) {
            float wv = wpg[o * 8 + c];
            s0 += dw[c][0] * wv; s1 += dw[c][1] * wv;
            s2 += dw[c][2] * wv; s3 += dw[c][3] * wv;
        }
        float4 ov = {s0, s1, s2, s3};
        *(float4*)(dstbase + (size_t)o * HW + n) = ov;
    }
}

// ---------------- K3: linear attention, plane input, channels-last bf16 out ----------------
__launch_bounds__(256)
__global__ void k3_attn(const float* __restrict__ qkv_pl, const float* __restrict__ agg_pl,
                        ushort* __restrict__ out_cl) {
    __shared__ float vk_partial[4][72];
    __shared__ float vk_s[72];
    int h = blockIdx.x;
    int b = blockIdx.y;
    const float* src = (h < 32) ? (qkv_pl + ((size_t)b * TD3 + h * 24) * HW)
                                : (agg_pl + ((size_t)b * TD3 + (h - 32) * 24) * HW);
    const float* kp = src + (size_t)8 * HW;
    const float* vp = src + (size_t)16 * HW;
    int t = threadIdx.x;
    float vk[9][8];
#pragma unroll
    for (int e = 0; e < 9; e++)
#pragma unroll
        for (int d = 0; d < 8; d++) vk[e][d] = 0.f;

#pragma unroll
    for (int it = 0; it < 4; it++) {
        int n4 = (t + it * 256) * 4;
        float4 kf[8], vf[8];
#pragma unroll
        for (int d = 0; d < 8; d++) kf[d] = *(const float4*)(kp + (size_t)d * HW + n4);
#pragma unroll
        for (int e = 0; e < 8; e++) vf[e] = *(const float4*)(vp + (size_t)e * HW + n4);
#pragma unroll
        for (int d = 0; d < 8; d++) {
            kf[d].x = fmaxf(kf[d].x, 0.f); kf[d].y = fmaxf(kf[d].y, 0.f);
            kf[d].z = fmaxf(kf[d].z, 0.f); kf[d].w = fmaxf(kf[d].w, 0.f);
        }
#pragma unroll
        for (int e = 0; e < 8; e++)
#pragma unroll
            for (int d = 0; d < 8; d++)
                vk[e][d] += vf[e].x * kf[d].x + vf[e].y * kf[d].y + vf[e].z * kf[d].z + vf[e].w * kf[d].w;
#pragma unroll
        for (int d = 0; d < 8; d++) vk[8][d] += kf[d].x + kf[d].y + kf[d].z + kf[d].w;
    }
#pragma unroll
    for (int e = 0; e < 9; e++)
#pragma unroll
        for (int d = 0; d < 8; d++) {
            float v = vk[e][d];
            for (int off = 32; off > 0; off >>= 1) v += __shfl_xor(v, off);
            vk[e][d] = v;
        }
    int w = t >> 6, l = t & 63;
    if (l == 0) {
#pragma unroll
        for (int e = 0; e < 9; e++)
#pragma unroll
            for (int d = 0; d < 8; d++) vk_partial[w][e * 8 + d] = vk[e][d];
    }
    __syncthreads();
    if (t < 72) vk_s[t] = vk_partial[0][t] + vk_partial[1][t] + vk_partial[2][t] + vk_partial[3][t];
    __syncthreads();
    float vkf[9][8];
#pragma unroll
    for (int e = 0; e < 9; e++)
#pragma unroll
        for (int d = 0; d < 8; d++) vkf[e][d] = vk_s[e * 8 + d];

    ushort* dst = out_cl + (size_t)b * HW * TD2 + h * 8;
#pragma unroll
    for (int it = 0; it < 4; it++) {
        int n4 = (t + it * 256) * 4;
        float qa[4][8];
#pragma unroll
        for (int d = 0; d < 8; d++) {
            float4 q4 = *(const float4*)(src + (size_t)d * HW + n4);
            qa[0][d] = fmaxf(q4.x, 0.f); qa[1][d] = fmaxf(q4.y, 0.f);
            qa[2][d] = fmaxf(q4.z, 0.f); qa[3][d] = fmaxf(q4.w, 0.f);
        }
#pragma unroll
        for (int j = 0; j < 4; j++) {
            float o[9];
#pragma unroll
            for (int e = 0; e < 9; e++) {
                float s = 0.f;
#pragma unroll
                for (int d = 0; d < 8; d++) s += vkf[e][d] * qa[j][d];
                o[e] = s;
            }
            float inv = 1.f / (o[8] + 1e-15f);
            uint4 ov;
            ov.x = pack2(o[0] * inv, o[1] * inv); ov.y = pack2(o[2] * inv, o[3] * inv);
            ov.z = pack2(o[4] * inv, o[5] * inv); ov.w = pack2(o[6] * inv, o[7] * inv);
            *(uint4*)(dst + (size_t)(n4 + j) * TD2) = ov;
        }
    }
}

// ---------------- K4: proj GEMM (split-A on w_proj) + BN + residual ----------------
__launch_bounds__(256)
__global__ void k4_proj(const ushort* __restrict__ out_cl, const float* __restrict__ w_proj,
                        const float* __restrict__ x, const float* __restrict__ gamma,
                        const float* __restrict__ beta, const float* __restrict__ mean,
                        const float* __restrict__ var_, float* __restrict__ out) {
    __shared__ ushort Ah[128][40];
    __shared__ ushort Al[128][40];
    __shared__ ushort Bld[128][40];
    int b = blockIdx.z;
    int n0 = blockIdx.x * 128;
    int c0 = blockIdx.y * 128;
    int t = threadIdx.x;
    int w = t >> 6, l = t & 63;
    int wc = (w >> 1) * 64, wn = (w & 1) * 64;
    f32x4 acc[4][4];
#pragma unroll
    for (int m = 0; m < 4; m++)
#pragma unroll
        for (int o = 0; o < 4; o++)
#pragma unroll
            for (int r = 0; r < 4; r++) acc[m][o][r] = 0.f;

    const float* Apf = w_proj + (size_t)c0 * TD2;
    const ushort* Bp = out_cl + ((size_t)b * HW + n0) * TD2;

    for (int k0 = 0; k0 < TD2; k0 += 32) {
#pragma unroll
        for (int it = 0; it < 2; it++) {
            int id = t + it * 256;
            int r = id >> 2, q = id & 3;
            const float* src = Apf + (size_t)r * TD2 + k0 + q * 8;
            float f[8];
            *(float4*)&f[0] = *(const float4*)src;
            *(float4*)&f[4] = *(const float4*)(src + 4);
            ushort hi[8]; float lo[8];
#pragma unroll
            for (int j = 0; j < 8; j++) { hi[j] = f2bf(f[j]); lo[j] = f[j] - bf2f(hi[j]); }
            uint4 hv, lv;
            hv.x = (uint)hi[0] | ((uint)hi[1] << 16); hv.y = (uint)hi[2] | ((uint)hi[3] << 16);
            hv.z = (uint)hi[4] | ((uint)hi[5] << 16); hv.w = (uint)hi[6] | ((uint)hi[7] << 16);
            lv.x = pack2(lo[0], lo[1]); lv.y = pack2(lo[2], lo[3]);
            lv.z = pack2(lo[4], lo[5]); lv.w = pack2(lo[6], lo[7]);
            *(uint4*)&Ah[r][q * 8] = hv;
            *(uint4*)&Al[r][q * 8] = lv;
        }
#pragma unroll
        for (int it = 0; it < 2; it++) {
            int id = t + it * 256;
            int r = id >> 2, q = id & 3;
            uint4 v = *(const uint4*)(Bp + (size_t)r * TD2 + k0 + q * 8);
            *(uint4*)&Bld[r][q * 8] = v;
        }
        __syncthreads();
        bf16x8 ah[4], al[4], bf[4];
#pragma unroll
        for (int m = 0; m < 4; m++) {
            ah[m] = *(const bf16x8*)&Ah[wc + m * 16 + (l & 15)][(l >> 4) * 8];
            al[m] = *(const bf16x8*)&Al[wc + m * 16 + (l & 15)][(l >> 4) * 8];
        }
#pragma unroll
        for (int ni = 0; ni < 4; ni++) bf[ni] = *(const bf16x8*)&Bld[wn + ni * 16 + (l & 15)][(l >> 4) * 8];
#pragma unroll
        for (int m = 0; m < 4; m++)
#pragma unroll
            for (int ni = 0; ni < 4; ni++) {
                acc[m][ni] = __builtin_amdgcn_mfma_f32_16x16x32_bf16(ah[m], bf[ni], acc[m][ni], 0, 0, 0);
                acc[m][ni] = __builtin_amdgcn_mfma_f32_16x16x32_bf16(al[m], bf[ni], acc[m][ni], 0, 0, 0);
            }
        __syncthreads();
    }
#pragma unroll
    for (int m = 0; m < 4; m++) {
        int cb = c0 + wc + m * 16 + (l >> 4) * 4;
        float sc[4], mn[4], bt[4];
#pragma unroll
        for (int r = 0; r < 4; r++) {
            sc[r] = gamma[cb + r] * rsqrtf(var_[cb + r] + 1e-5f);
            mn[r] = mean[cb + r];
            bt[r] = beta[cb + r];
        }
#pragma unroll
        for (int ni = 0; ni < 4; ni++) {
            int n = n0 + wn + ni * 16 + (l & 15);
#pragma unroll
            for (int r = 0; r < 4; r++) {
                size_t idx = ((size_t)b * CC + cb + r) * HW + n;
                out[idx] = x[idx] + (acc[m][ni][r] - mn[r]) * sc[r] + bt[r];
            }
        }
    }
}

extern "C" void kernel_launch(void* const* d_in, const int* in_sizes, int n_in,
                              void* d_out, int out_size, void* d_ws, size_t ws_size,
                              hipStream_t stream) {
    const float* x      = (const float*)d_in[0];
    const float* w_qkv  = (const float*)d_in[1];
    const float* w_dw   = (const float*)d_in[2];
    const float* w_pw   = (const float*)d_in[3];
    const float* w_proj = (const float*)d_in[4];
    const float* gamma  = (const float*)d_in[5];
    const float* beta   = (const float*)d_in[6];
    const float* mean   = (const float*)d_in[7];
    const float* var_   = (const float*)d_in[8];
    float* out = (float*)d_out;

    // Per-batch workspace (bytes): x_cl bf16 + qkv f32 planes + agg f32 planes + out_cl bf16
    const size_t per_batch = (size_t)HW * CC * 2 + (size_t)HW * TD3 * 4 * 2 + (size_t)HW * TD2 * 2;
    int cb = 16;
    while (cb > 1 && (size_t)cb * per_batch > ws_size) cb >>= 1;

    char* ws = (char*)d_ws;
    ushort* x_cl   = (ushort*)ws;
    float*  qkv_pl = (float*)(ws + (size_t)cb * HW * CC * 2);
    float*  agg_pl = (float*)(ws + (size_t)cb * HW * CC * 2 + (size_t)cb * HW * TD3 * 4);
    ushort* out_cl = (ushort*)(ws + (size_t)cb * HW * CC * 2 + (size_t)cb * HW * TD3 * 8);

    for (int b0 = 0; b0 < BB; b0 += cb) {
        const float* xc = x + (size_t)b0 * CC * HW;
        float* oc = out + (size_t)b0 * CC * HW;
        k0_transpose<<<dim3(64, 4, cb), 256, 0, stream>>>(xc, x_cl);
        k1_qkv<<<dim3(32, 6, cb), 256, 0, stream>>>(x_cl, w_qkv, qkv_pl);
        k2_dwpw<<<dim3(96, 4, cb), 256, 0, stream>>>(qkv_pl, w_dw, w_pw, agg_pl);
        k3_attn<<<dim3(64, cb), 256, 0, stream>>>(qkv_pl, agg_pl, out_cl);
        k4_proj<<<dim3(32, 2, cb), 256, 0, stream>>>(out_cl, w_proj, xc, gamma, beta, mean, var_, oc);
    }
}